// Round 2
// baseline (236.990 us; speedup 1.0000x reference)
//
#include <hip/hip_runtime.h>
#include <math.h>

// CBOW hierarchical-softmax loss — R5: pin gather MLP + distribute transcendentals.
//   B=65536, C=10, D=18, E=128.
//   loss[b] = -sum_d log( p_d + 1e-9 ), p_d = (code==1) ? s_d : 1 - s_d,
//   s_d = sigmoid(u_d . v), v = mean_c in_embed[ctx[b,c]].
//
// R1 lesson: p MUST be computed literally as fp32 reference (s, then 1-s);
//   precise expf/logf (not __expf).
// R4 post-mortem: readfirstlane scalarized the index loads (SGPR 32->64) but
//   the scheduler re-sank the 14 gathers next to their consumers (VGPR fell
//   to 32 -> MLP ~2). Source ordering alone does not bind.
// R5 fixes:
//   (a) __builtin_amdgcn_sched_barrier(0) after the 14 gather issues pins
//       them as one cluster -> 14 loads in flight per wave. No math change.
//   (b) Transcendental distribution: previously all 32 lanes of a half
//       redundantly computed the same 9 expf/logf chains (~540 of ~900 VALU
//       cycles/wave). Now lane sel=lane&15 owns one d via a cndmask select
//       tree (compile-time indices only — no scratch), codes bit-packed in
//       a scalar mask. ONE transcendental pass instead of nine. Per-term
//       bits identical; only the final 9-term sum is reassociated
//       (balanced tree, ~1 ulp). Dot butterfly keeps exact 16..1 order.

constexpr int Bn = 65536;
constexpr int Cn = 10;
constexpr int Dn = 18;
constexpr float EPS = 1e-9f;

__global__ __launch_bounds__(256) void cbow_hs_kernel(
    const int* __restrict__ ctx,          // [B,C]
    const int* __restrict__ nodes,        // [B,D]
    const int* __restrict__ codes,        // [B,D]
    const float* __restrict__ in_embed,   // [V,E]
    const float* __restrict__ node_embed, // [N,E]
    float* __restrict__ out)              // [B]
{
    const int lane = threadIdx.x & 63;
    const int sl   = lane & 31;          // sub-lane within half
    const bool hi  = lane >= 32;         // which half
    // b uniform across the wave -> SGPR, index loads select as scalar loads.
    int b = (int)(blockIdx.x << 2) + (int)(threadIdx.x >> 6);
    b = __builtin_amdgcn_readfirstlane(b);

    // ---- index preload: wave-uniform -> scalar (SMEM) loads -------------
    const int* __restrict__ cp = ctx   + b * Cn;
    const int* __restrict__ np = nodes + b * Dn;
    const int* __restrict__ kp = codes + b * Dn;
    int cidx[Cn];
    #pragma unroll
    for (int k = 0; k < Cn; ++k) cidx[k] = cp[k];
    int nidx[Dn];
    #pragma unroll
    for (int k = 0; k < Dn; ++k) nidx[k] = np[k];
    int code[Dn];
    #pragma unroll
    for (int k = 0; k < Dn; ++k) code[k] = kp[k];

    // bit-pack codes: bit i of cm_even = (code[2i]==1), cm_odd = (code[2i+1]==1)
    int cm_even = 0, cm_odd = 0;
    #pragma unroll
    for (int i = 0; i < Dn / 2; ++i) {
        cm_even |= (code[2 * i]     == 1 ? 1 : 0) << i;
        cm_odd  |= (code[2 * i + 1] == 1 ? 1 : 0) << i;
    }

    const float4* __restrict__ in4 = (const float4*)in_embed;    // 32 f4/row
    const float4* __restrict__ ne4 = (const float4*)node_embed;

    // ---- issue ALL 14 gathers, then pin with a scheduling barrier -------
    // halves gather DIFFERENT rows in the same instruction:
    //   half 0 handles even c/d, half 1 odd.
    float4 e[Cn / 2];
    #pragma unroll
    for (int k = 0; k < Cn / 2; ++k) {
        const int idx = hi ? cidx[2 * k + 1] : cidx[2 * k];
        e[k] = in4[(size_t)idx * 32 + sl];
    }
    float4 u[Dn / 2];
    #pragma unroll
    for (int i = 0; i < Dn / 2; ++i) {
        const int idx = hi ? nidx[2 * i + 1] : nidx[2 * i];
        u[i] = ne4[(size_t)idx * 32 + sl];
    }
    // Nothing may move across this point: all 14 loads stay issued above,
    // all consumers stay below -> 14 outstanding gathers per wave.
    __builtin_amdgcn_sched_barrier(0);

    // ---- v = mean of 10 context rows (same add order as R3/R4) ----------
    float4 vs = make_float4(0.f, 0.f, 0.f, 0.f);
    #pragma unroll
    for (int k = 0; k < Cn / 2; ++k) {
        vs.x += e[k].x; vs.y += e[k].y; vs.z += e[k].z; vs.w += e[k].w;
    }
    // combine halves: after this both halves hold the full context sum
    vs.x += __shfl_xor(vs.x, 32, 64);
    vs.y += __shfl_xor(vs.y, 32, 64);
    vs.z += __shfl_xor(vs.z, 32, 64);
    vs.w += __shfl_xor(vs.w, 32, 64);
    float4 v;
    v.x = vs.x * (1.0f / Cn); v.y = vs.y * (1.0f / Cn);
    v.z = vs.z * (1.0f / Cn); v.w = vs.w * (1.0f / Cn);

    // ---- 18 dots: half 0 -> even d, half 1 -> odd d (9 each) -----------
    float pd[Dn / 2];
    #pragma unroll
    for (int i = 0; i < Dn / 2; ++i) {
        pd[i] = u[i].x * v.x + u[i].y * v.y + u[i].z * v.z + u[i].w * v.w;
    }

    // 5-level butterfly within each 32-lane half, EXACT R3/R4 order (16..1)
    #pragma unroll
    for (int i = 0; i < Dn / 2; ++i) {
        #pragma unroll
        for (int m = 16; m >= 1; m >>= 1)
            pd[i] += __shfl_xor(pd[i], m, 64);
    }

    // ---- ONE distributed transcendental pass (was 9 redundant passes) ---
    // sel = lane&15 owns term i=sel (i=0..8 valid; 9..15 padded, masked to 0).
    const int sel = lane & 15;
    // compile-time-indexed cndmask select tree (no scratch, rule #20)
    const float x01   = (sel & 1) ? pd[1] : pd[0];
    const float x23   = (sel & 1) ? pd[3] : pd[2];
    const float x45   = (sel & 1) ? pd[5] : pd[4];
    const float x67   = (sel & 1) ? pd[7] : pd[6];
    const float x0123 = (sel & 2) ? x23 : x01;
    const float x4567 = (sel & 2) ? x67 : x45;
    const float xlow  = (sel & 4) ? x4567 : x0123;
    const float x     = (sel & 8) ? pd[8] : xlow;   // sel 9..15: pad with pd[8]
    const int   cm    = hi ? cm_odd : cm_even;
    const int   cd    = (cm >> sel) & 1;            // sel>8 -> 0, masked below

    // Literal fp32 reference semantics (bitwise same per-term as before):
    const float s = 1.0f / (1.0f + expf(-x));
    const float p = (cd == 1) ? s : 1.0f - s;
    float loss = (sel < Dn / 2) ? -logf(p + EPS) : 0.0f;

    // sum the 9 distributed terms within each 16-lane group (balanced tree)
    loss += __shfl_xor(loss, 1, 64);
    loss += __shfl_xor(loss, 2, 64);
    loss += __shfl_xor(loss, 4, 64);
    loss += __shfl_xor(loss, 8, 64);
    // half 0 holds even-d sum, half 1 odd-d sum
    loss += __shfl_xor(loss, 32, 64);

    if (lane == 0) out[b] = loss;
}

extern "C" void kernel_launch(void* const* d_in, const int* in_sizes, int n_in,
                              void* d_out, int out_size, void* d_ws, size_t ws_size,
                              hipStream_t stream) {
    const int*   ctx        = (const int*)d_in[0];
    const int*   path_nodes = (const int*)d_in[1];
    const int*   codes      = (const int*)d_in[2];
    const float* in_embed   = (const float*)d_in[3];
    const float* node_embed = (const float*)d_in[4];
    float*       out        = (float*)d_out;

    dim3 grid(Bn / 4);
    dim3 block(256);
    cbow_hs_kernel<<<grid, block, 0, stream>>>(ctx, path_nodes, codes,
                                               in_embed, node_embed, out);
}

// Round 3
// 231.290 us; speedup vs baseline: 1.0246x; 1.0246x over previous
//
#include <hip/hip_runtime.h>
#include <math.h>

// CBOW hierarchical-softmax loss — R6: inline-asm forced gather MLP.
//   B=65536, C=10, D=18, E=128.
//   loss[b] = -sum_d log( p_d + 1e-9 ), p_d = (code==1) ? s_d : 1 - s_d,
//   s_d = sigmoid(u_d . v), v = mean_c in_embed[ctx[b,c]].
//
// R1 lesson: p computed literally as fp32 reference (s, then 1-s); precise
//   expf/logf.
// R5 post-mortem: transcendental distribution halved VALUBusy (52->24%) with
//   ZERO dur change -> purely memory-side limited. VGPR stayed 32 -> the
//   sched_barrier(0) did NOT form the gather cluster (pre-RA scheduler sank
//   loads before the machine scheduler saw the barrier). 14 in-flight
//   dwordx4 need 56 result VGPRs; 32 proves MLP ~2.
// R6: the only binding tool is inline-asm global_load_dwordx4 with explicit
//   "=v" destinations — RA must keep all 14 results live, guaranteeing a
//   14-deep issue cluster per wave. Split wait: vmcnt(9) -> consume the 5
//   context rows while the 9 node rows are still in flight, then vmcnt(0).
//   (vmcnt(9) is safe against any stray vmem: the u-loads are the LAST 9
//   vmem ops issued, so outstanding<=9 implies all e-loads landed.)
//   Rule #18: sched_barrier(0) right after each inline-asm waitcnt so
//   consumers cannot hoist above it.
// Decides: latency-bound (expect ~95-110 us, hbm ~4.5 TB/s) vs random-gather
//   throughput ceiling (flat ~130 us -> roofline).

typedef float f32x4 __attribute__((ext_vector_type(4)));

constexpr int Bn = 65536;
constexpr int Cn = 10;
constexpr int Dn = 18;
constexpr float EPS = 1e-9f;

__global__ __launch_bounds__(256) void cbow_hs_kernel(
    const int* __restrict__ ctx,          // [B,C]
    const int* __restrict__ nodes,        // [B,D]
    const int* __restrict__ codes,        // [B,D]
    const float* __restrict__ in_embed,   // [V,E]
    const float* __restrict__ node_embed, // [N,E]
    float* __restrict__ out)              // [B]
{
    const int lane = threadIdx.x & 63;
    const int sl   = lane & 31;          // sub-lane within half
    const bool hi  = lane >= 32;         // which half
    // b uniform across the wave -> SGPR, index loads select as scalar loads.
    int b = (int)(blockIdx.x << 2) + (int)(threadIdx.x >> 6);
    b = __builtin_amdgcn_readfirstlane(b);

    // ---- index preload: wave-uniform -> scalar (SMEM) loads -------------
    const int* __restrict__ cp = ctx   + b * Cn;
    const int* __restrict__ np = nodes + b * Dn;
    const int* __restrict__ kp = codes + b * Dn;
    int cidx[Cn];
    #pragma unroll
    for (int k = 0; k < Cn; ++k) cidx[k] = cp[k];
    int nidx[Dn];
    #pragma unroll
    for (int k = 0; k < Dn; ++k) nidx[k] = np[k];
    int code[Dn];
    #pragma unroll
    for (int k = 0; k < Dn; ++k) code[k] = kp[k];

    // bit-pack codes: bit i of cm_even = (code[2i]==1), cm_odd = (code[2i+1]==1)
    int cm_even = 0, cm_odd = 0;
    #pragma unroll
    for (int i = 0; i < Dn / 2; ++i) {
        cm_even |= (code[2 * i]     == 1 ? 1 : 0) << i;
        cm_odd  |= (code[2 * i + 1] == 1 ? 1 : 0) << i;
    }

    // 32-bit voffset + scalar 64-bit base (tables are 51 MB < 4 GB):
    //   addr = base + idx*512 + sl*16
    const unsigned long long in_base = (unsigned long long)in_embed;
    const unsigned long long ne_base = (unsigned long long)node_embed;
    const unsigned vsl = (unsigned)sl << 4;

    // ---- forced 14-deep gather cluster (halves gather different rows) ---
    f32x4 e[Cn / 2];
    #pragma unroll
    for (int k = 0; k < Cn / 2; ++k) {
        const int idx = hi ? cidx[2 * k + 1] : cidx[2 * k];
        const unsigned vo = ((unsigned)idx << 9) + vsl;
        asm volatile("global_load_dwordx4 %0, %1, %2"
                     : "=v"(e[k]) : "v"(vo), "s"(in_base));
    }
    f32x4 u[Dn / 2];
    #pragma unroll
    for (int i = 0; i < Dn / 2; ++i) {
        const int idx = hi ? nidx[2 * i + 1] : nidx[2 * i];
        const unsigned vo = ((unsigned)idx << 9) + vsl;
        asm volatile("global_load_dwordx4 %0, %1, %2"
                     : "=v"(u[i]) : "v"(vo), "s"(ne_base));
    }

    // wait until only the 9 node loads are outstanding -> all e's landed
    asm volatile("s_waitcnt vmcnt(9)" ::: "memory");
    __builtin_amdgcn_sched_barrier(0);

    // ---- v = mean of 10 context rows (same add order as R3/R4/R5) -------
    float vsx = 0.f, vsy = 0.f, vsz = 0.f, vsw = 0.f;
    #pragma unroll
    for (int k = 0; k < Cn / 2; ++k) {
        vsx += e[k].x; vsy += e[k].y; vsz += e[k].z; vsw += e[k].w;
    }
    // combine halves: after this both halves hold the full context sum
    vsx += __shfl_xor(vsx, 32, 64);
    vsy += __shfl_xor(vsy, 32, 64);
    vsz += __shfl_xor(vsz, 32, 64);
    vsw += __shfl_xor(vsw, 32, 64);
    const float vx = vsx * (1.0f / Cn), vy = vsy * (1.0f / Cn);
    const float vz = vsz * (1.0f / Cn), vw = vsw * (1.0f / Cn);

    // wait for the node rows
    asm volatile("s_waitcnt vmcnt(0)" ::: "memory");
    __builtin_amdgcn_sched_barrier(0);

    // ---- 18 dots: half 0 -> even d, half 1 -> odd d (9 each) -----------
    float pd[Dn / 2];
    #pragma unroll
    for (int i = 0; i < Dn / 2; ++i) {
        pd[i] = u[i].x * vx + u[i].y * vy + u[i].z * vz + u[i].w * vw;
    }

    // 5-level butterfly within each 32-lane half, EXACT R3/R4/R5 order
    #pragma unroll
    for (int i = 0; i < Dn / 2; ++i) {
        #pragma unroll
        for (int m = 16; m >= 1; m >>= 1)
            pd[i] += __shfl_xor(pd[i], m, 64);
    }

    // ---- ONE distributed transcendental pass (R5, verified absmax 0) ----
    // sel = lane&15 owns term i=sel (i=0..8 valid; 9..15 padded, masked).
    const int sel = lane & 15;
    const float x01   = (sel & 1) ? pd[1] : pd[0];
    const float x23   = (sel & 1) ? pd[3] : pd[2];
    const float x45   = (sel & 1) ? pd[5] : pd[4];
    const float x67   = (sel & 1) ? pd[7] : pd[6];
    const float x0123 = (sel & 2) ? x23 : x01;
    const float x4567 = (sel & 2) ? x67 : x45;
    const float xlow  = (sel & 4) ? x4567 : x0123;
    const float x     = (sel & 8) ? pd[8] : xlow;   // sel 9..15: pad with pd[8]
    const int   cm    = hi ? cm_odd : cm_even;
    const int   cd    = (cm >> sel) & 1;

    // Literal fp32 reference semantics (bitwise same per-term as before):
    const float s = 1.0f / (1.0f + expf(-x));
    const float p = (cd == 1) ? s : 1.0f - s;
    float loss = (sel < Dn / 2) ? -logf(p + EPS) : 0.0f;

    // sum the 9 distributed terms within each 16-lane group (balanced tree)
    loss += __shfl_xor(loss, 1, 64);
    loss += __shfl_xor(loss, 2, 64);
    loss += __shfl_xor(loss, 4, 64);
    loss += __shfl_xor(loss, 8, 64);
    // half 0 holds even-d sum, half 1 odd-d sum
    loss += __shfl_xor(loss, 32, 64);

    if (lane == 0) out[b] = loss;
}

extern "C" void kernel_launch(void* const* d_in, const int* in_sizes, int n_in,
                              void* d_out, int out_size, void* d_ws, size_t ws_size,
                              hipStream_t stream) {
    const int*   ctx        = (const int*)d_in[0];
    const int*   path_nodes = (const int*)d_in[1];
    const int*   codes      = (const int*)d_in[2];
    const float* in_embed   = (const float*)d_in[3];
    const float* node_embed = (const float*)d_in[4];
    float*       out        = (float*)d_out;

    dim3 grid(Bn / 4);
    dim3 block(256);
    cbow_hs_kernel<<<grid, block, 0, stream>>>(ctx, path_nodes, codes,
                                               in_embed, node_embed, out);
}